// Round 7
// baseline (234.935 us; speedup 1.0000x reference)
//
#include <hip/hip_runtime.h>
#include <math.h>

#define L_ 2
#define BAT_ 32
#define A_ 64
#define B_ 1024
#define D_ 128
#define NBITS_ 1024
#define NW 32                 // u32 words per code (1024 bits)
#define NQROWS (L_*BAT_*A_)   // 4096
#define NDROWS (L_*BAT_*B_)   // 65536
#define NROWS (NQROWS + NDROWS) // 69632

// A LDS row: [hi 0..127 | lo 128..255 | pad 8] bf16 = 264 (132 dw ≡ 4 mod 32:
// frag start banks 4*col -> 2-way = free; 264%8==0 keeps b128 16-B alignment)
#define ARS 264

typedef __bf16 bf16x4 __attribute__((ext_vector_type(4)));
typedef __bf16 bf16x8 __attribute__((ext_vector_type(8)));
typedef float  f32x4  __attribute__((ext_vector_type(4)));

// -------- Stage 0: presplit r into bf16 hi|lo (runs once, 0.5 MB ws) -------
// rsp row (per bit): [hi 0..127 | lo 128..255] bf16.
__global__ __launch_bounds__(256) void split_r_kernel(
    const float* __restrict__ r, __bf16* __restrict__ rsp)
{
    int tid = blockIdx.x * 256 + threadIdx.x;   // 32768 threads
    int f = tid * 4;
    int row = f >> 7, cc = f & 127;
    float4 v = *(const float4*)(r + f);
    bf16x4 hi, lo;
    hi[0] = (__bf16)v.x; hi[1] = (__bf16)v.y;
    hi[2] = (__bf16)v.z; hi[3] = (__bf16)v.w;
    lo[0] = (__bf16)(v.x - (float)hi[0]);
    lo[1] = (__bf16)(v.y - (float)hi[1]);
    lo[2] = (__bf16)(v.z - (float)hi[2]);
    lo[3] = (__bf16)(v.w - (float)hi[3]);
    *(bf16x4*)(&rsp[(size_t)row * 256 + cc])       = hi;
    *(bf16x4*)(&rsp[(size_t)row * 256 + 128 + cc]) = lo;
}

// ---------------- Stage 1: LSH sign-hash (bf16-split MFMA) ------------------
// grid (NROWS/64 = 1088, NBITS/512 = 2), block 256 = 4 waves.
// Block: 64 rows x 512 bits; wave: 64 rows x 128 bits (4x8 of 16x16 tiles).
// A staged in LDS once (hi|lo, full K) -> ONE barrier. B-frags loaded directly
// from L1/L2-resident rsp (vmem pipe) — LDS traffic is ~32 b128/wave total,
// negligible vs 384 MFMA. 3 segments: hi*hi + lo*hi + hi*lo.
__global__ __launch_bounds__(256, 2) void hash_kernel(
    const float* __restrict__ qe, const float* __restrict__ de,
    const __bf16* __restrict__ rsp, unsigned int* __restrict__ codes_t)
{
    __shared__ __align__(16) __bf16 As[64 * ARS];   // 33792 B

    const int t = threadIdx.x;
    const int row0 = blockIdx.x * 64;   // 4096 % 64 == 0: no q/d straddle
    const int bit0 = blockIdx.y * 512;

    const float* abase = (row0 < NQROWS) ? (qe + (size_t)row0 * D_)
                                         : (de + (size_t)(row0 - NQROWS) * D_);

    // stage A: 64x128 fp32 -> bf16 hi|lo (8 float4 / thread)
    #pragma unroll
    for (int i = 0; i < 8; ++i) {
        int f = (t + i * 256) * 4;      // [0, 8192)
        int rr = f >> 7, cc = f & 127;
        float4 v = *(const float4*)(abase + (size_t)rr * D_ + cc);
        bf16x4 hi, lo;
        hi[0] = (__bf16)v.x; hi[1] = (__bf16)v.y;
        hi[2] = (__bf16)v.z; hi[3] = (__bf16)v.w;
        lo[0] = (__bf16)(v.x - (float)hi[0]);
        lo[1] = (__bf16)(v.y - (float)hi[1]);
        lo[2] = (__bf16)(v.z - (float)hi[2]);
        lo[3] = (__bf16)(v.w - (float)hi[3]);
        *(bf16x4*)(&As[rr * ARS + cc])       = hi;
        *(bf16x4*)(&As[rr * ARS + 128 + cc]) = lo;
    }
    __syncthreads();

    const int wv   = t >> 6;          // wave 0..3 -> bits wv*128..+127
    const int lane = t & 63;
    const int quad = lane >> 4;       // 0..3
    const int col  = lane & 15;       // 0..15
    const size_t bbase = (size_t)(bit0 + wv * 128) * 256;  // rsp elem offset

    f32x4 acc[4][8];
    #pragma unroll
    for (int ti = 0; ti < 4; ++ti)
        #pragma unroll
        for (int tj = 0; tj < 8; ++tj)
            acc[ti][tj] = (f32x4){0.f, 0.f, 0.f, 0.f};

    #pragma unroll
    for (int kk = 0; kk < 4; ++kk) {
        const int ko = kk * 32 + quad * 8;
        bf16x8 ah[4], al[4];
        #pragma unroll
        for (int ti = 0; ti < 4; ++ti) {
            const __bf16* p = &As[(ti * 16 + col) * ARS + ko];
            ah[ti] = *(const bf16x8*)(p);
            al[ti] = *(const bf16x8*)(p + 128);
        }
        bf16x8 bh[8];
        #pragma unroll
        for (int tj = 0; tj < 8; ++tj)
            bh[tj] = *(const bf16x8*)(&rsp[bbase + (size_t)(tj * 16 + col) * 256 + ko]);
        #pragma unroll
        for (int ti = 0; ti < 4; ++ti)
            #pragma unroll
            for (int tj = 0; tj < 8; ++tj)
                acc[ti][tj] = __builtin_amdgcn_mfma_f32_16x16x32_bf16(
                    ah[ti], bh[tj], acc[ti][tj], 0, 0, 0);      // hi*hi
        #pragma unroll
        for (int ti = 0; ti < 4; ++ti)
            #pragma unroll
            for (int tj = 0; tj < 8; ++tj)
                acc[ti][tj] = __builtin_amdgcn_mfma_f32_16x16x32_bf16(
                    al[ti], bh[tj], acc[ti][tj], 0, 0, 0);      // lo*hi
        bf16x8 bl[8];
        #pragma unroll
        for (int tj = 0; tj < 8; ++tj)
            bl[tj] = *(const bf16x8*)(&rsp[bbase + (size_t)(tj * 16 + col) * 256 + 128 + ko]);
        #pragma unroll
        for (int ti = 0; ti < 4; ++ti)
            #pragma unroll
            for (int tj = 0; tj < 8; ++tj)
                acc[ti][tj] = __builtin_amdgcn_mfma_f32_16x16x32_bf16(
                    ah[ti], bl[tj], acc[ti][tj], 0, 0, 0);      // hi*lo
    }

    // Sign-pack via ballot; C/D layout (m89): col=lane&15, row=quad*4+reg.
    // Wave covers 4 words (128 bits): lanes col<4 store word w=col.
    #pragma unroll
    for (int ti = 0; ti < 4; ++ti) {
        #pragma unroll
        for (int rg = 0; rg < 4; ++rg) {
            unsigned long long b[8];
            #pragma unroll
            for (int tj = 0; tj < 8; ++tj)
                b[tj] = __ballot(acc[ti][tj][rg] > 0.f);
            if (col < 4) {
                const int w = col;
                unsigned int lo16 = (unsigned int)(b[2 * w]     >> (16 * quad)) & 0xFFFFu;
                unsigned int hi16 = (unsigned int)(b[2 * w + 1] >> (16 * quad)) & 0xFFFFu;
                const int row = row0 + ti * 16 + quad * 4 + rg;
                const int wg  = (bit0 >> 5) + wv * 4 + w;
                codes_t[(size_t)wg * NROWS + row] = lo16 | (hi16 << 16);
            }
        }
    }
}

// ---------------- Stage 2: Hamming -> cos LUT -> mask -> out ----------------
// grid: 1024 blocks (l, b, 4 doc-chunks, 4 a-chunks of 16), block 256 = 1 doc.
// codes_t is word-major: all code loads lane-consecutive (coalesced).
__global__ __launch_bounds__(256) void simmat_kernel(
    const unsigned int* __restrict__ codes_t,
    const int* __restrict__ qtok, const int* __restrict__ dtok,
    float* __restrict__ out)
{
    __shared__ unsigned int qc[16 * 36];  // 16 a-rows, stride 36 (b128-aligned)
    __shared__ float lut[NBITS_ + 1];
    __shared__ float qm[16];

    const int blk  = blockIdx.x;
    const int ct   = blk & 3;
    const int asub = (blk >> 2) & 3;
    const int b    = (blk >> 4) & 31;
    const int l    = blk >> 9;
    const int t    = threadIdx.x;

    for (int h = t; h <= NBITS_; h += 256)
        lut[h] = cosf((float)M_PI / (float)NBITS_ * (float)h);

    const int a0 = asub * 16;
    const int qrow0 = (l * BAT_ + b) * A_ + a0;
    for (int i = 0; i < 2; ++i) {
        int idx = i * 256 + t;            // [0, 512)
        int w = idx >> 4, a = idx & 15;
        qc[a * 36 + w] = codes_t[(size_t)w * NROWS + qrow0 + a];
    }
    if (t < 16) qm[t] = (qtok[b * A_ + a0 + t] != 0) ? 1.f : 0.f;
    __syncthreads();

    const int c = ct * 256 + t;
    const size_t drow = (size_t)NQROWS + (size_t)(l * BAT_ + b) * B_ + c;
    unsigned int dc[NW];
    #pragma unroll
    for (int w = 0; w < NW; ++w) dc[w] = codes_t[(size_t)w * NROWS + drow];
    const float dm = (dtok[b * B_ + c] != 0) ? 1.f : 0.f;

    float* obase = out + ((size_t)((b * L_ + l) * A_ + a0)) * B_ + c;
    #pragma unroll
    for (int ai = 0; ai < 16; ++ai) {
        int ham = 0;
        #pragma unroll
        for (int m = 0; m < 8; ++m) {
            uint4 qv = *(const uint4*)(&qc[ai * 36 + m * 4]);
            ham += __popc(qv.x ^ dc[4 * m])     + __popc(qv.y ^ dc[4 * m + 1])
                 + __popc(qv.z ^ dc[4 * m + 2]) + __popc(qv.w ^ dc[4 * m + 3]);
        }
        obase[(size_t)ai * B_] = lut[ham] * qm[ai] * dm;
    }
}

extern "C" void kernel_launch(void* const* d_in, const int* in_sizes, int n_in,
                              void* d_out, int out_size, void* d_ws, size_t ws_size,
                              hipStream_t stream) {
    const float* qe  = (const float*)d_in[0];  // [L,BAT,A,D]
    const float* de  = (const float*)d_in[1];  // [L,BAT,B,D]
    const int* qtok  = (const int*)d_in[2];    // [BAT,A]
    const int* dtok  = (const int*)d_in[3];    // [BAT,B]
    const float* r   = (const float*)d_in[4];  // [NBITS,D]
    float* out = (float*)d_out;                // [BAT,L,A,B] fp32

    // ws layout: [0, 512KB) r presplit; [512KB, +8.9MB) transposed codes
    __bf16* rsp = (__bf16*)d_ws;
    unsigned int* codes_t = (unsigned int*)((char*)d_ws + 524288);

    split_r_kernel<<<128, 256, 0, stream>>>(r, rsp);
    dim3 g1(NROWS / 64, NBITS_ / 512);
    hash_kernel<<<g1, 256, 0, stream>>>(qe, de, rsp, codes_t);
    simmat_kernel<<<L_ * BAT_ * 4 * 4, 256, 0, stream>>>(codes_t, qtok, dtok, out);
}

// Round 8
// 173.079 us; speedup vs baseline: 1.3574x; 1.3574x over previous
//
#include <hip/hip_runtime.h>
#include <math.h>

#define L_ 2
#define BAT_ 32
#define A_ 64
#define B_ 1024
#define D_ 128
#define NBITS_ 1024
#define NW 32                 // u32 words per code (1024 bits)
#define NQROWS (L_*BAT_*A_)   // 4096
#define NDROWS (L_*BAT_*B_)   // 65536
#define NROWS (NQROWS + NDROWS) // 69632

#define TM 128                // rows per block
#define TN 128                // bits per block
#define KH 64                 // K staged in halves
// LDS row: [hi 0..63 | lo 64..127 | pad 8] bf16 -> stride 136 elts = 272 B
#define RS 136

typedef __bf16 bf16x4 __attribute__((ext_vector_type(4)));
typedef __bf16 bf16x8 __attribute__((ext_vector_type(8)));
typedef float  f32x4  __attribute__((ext_vector_type(4)));

// ---------------- Stage 1: LSH sign-hash (bf16-split MFMA + ballot pack) ----
// EXACT R5 structure (87 us measured) — only the epilogue store is transposed
// to codes_t[word][row] so stage 2 reads coalesce.
__global__ __launch_bounds__(256) void hash_kernel(
    const float* __restrict__ qe, const float* __restrict__ de,
    const float* __restrict__ r, unsigned int* __restrict__ codes_t)
{
    __shared__ __align__(16) __bf16 As[TM * RS];   // 34816 B
    __shared__ __align__(16) __bf16 Bs[TN * RS];   // 34816 B

    const int t = threadIdx.x;
    const int row0 = blockIdx.x * TM;   // 4096 % 128 == 0: no q/d straddle
    const int bit0 = blockIdx.y * TN;

    const float* abase = (row0 < NQROWS) ? (qe + (size_t)row0 * D_)
                                         : (de + (size_t)(row0 - NQROWS) * D_);
    const float* bbase = r + (size_t)bit0 * D_;

    const int wv   = t >> 6;          // wave 0..3
    const int lane = t & 63;
    const int quad = lane >> 4;       // 0..3
    const int col  = lane & 15;       // 0..15
    const int wrow = (wv >> 1) * 64;  // wave's row offset in block tile
    const int wbit = (wv & 1) * 64;   // wave's bit offset in block tile

    f32x4 acc[4][4];
    #pragma unroll
    for (int ti = 0; ti < 4; ++ti)
        #pragma unroll
        for (int tj = 0; tj < 4; ++tj)
            acc[ti][tj] = (f32x4){0.f, 0.f, 0.f, 0.f};

    #pragma unroll
    for (int ks = 0; ks < D_; ks += KH) {
        if (ks) __syncthreads();
        // stage 128x64 fp32 slice of A and B, split into bf16 hi|lo in LDS
        #pragma unroll
        for (int i = 0; i < 8; ++i) {
            int f = (t + i * 256) * 4;      // flat idx in 128x64 tile
            int rr = f >> 6, cc = f & 63;
            float4 v = *(const float4*)(abase + (size_t)rr * D_ + ks + cc);
            bf16x4 hi, lo;
            hi[0] = (__bf16)v.x; hi[1] = (__bf16)v.y;
            hi[2] = (__bf16)v.z; hi[3] = (__bf16)v.w;
            lo[0] = (__bf16)(v.x - (float)hi[0]);
            lo[1] = (__bf16)(v.y - (float)hi[1]);
            lo[2] = (__bf16)(v.z - (float)hi[2]);
            lo[3] = (__bf16)(v.w - (float)hi[3]);
            *(bf16x4*)(&As[rr * RS + cc])      = hi;
            *(bf16x4*)(&As[rr * RS + 64 + cc]) = lo;
        }
        #pragma unroll
        for (int i = 0; i < 8; ++i) {
            int f = (t + i * 256) * 4;
            int rr = f >> 6, cc = f & 63;
            float4 v = *(const float4*)(bbase + (size_t)rr * D_ + ks + cc);
            bf16x4 hi, lo;
            hi[0] = (__bf16)v.x; hi[1] = (__bf16)v.y;
            hi[2] = (__bf16)v.z; hi[3] = (__bf16)v.w;
            lo[0] = (__bf16)(v.x - (float)hi[0]);
            lo[1] = (__bf16)(v.y - (float)hi[1]);
            lo[2] = (__bf16)(v.z - (float)hi[2]);
            lo[3] = (__bf16)(v.w - (float)hi[3]);
            *(bf16x4*)(&Bs[rr * RS + cc])      = hi;
            *(bf16x4*)(&Bs[rr * RS + 64 + cc]) = lo;
        }
        __syncthreads();

        // 3 segments: (A-off, B-off) = (hi,hi), (hi,lo), (lo,hi)
        #pragma unroll
        for (int seg = 0; seg < 3; ++seg) {
            const int ao = (seg == 2) ? 64 : 0;
            const int bo = (seg == 1) ? 64 : 0;
            #pragma unroll
            for (int kk = 0; kk < KH; kk += 32) {
                bf16x8 af[4], bfr[4];
                #pragma unroll
                for (int ti = 0; ti < 4; ++ti)
                    af[ti] = *(const bf16x8*)(
                        &As[(wrow + ti * 16 + col) * RS + ao + kk + quad * 8]);
                #pragma unroll
                for (int tj = 0; tj < 4; ++tj)
                    bfr[tj] = *(const bf16x8*)(
                        &Bs[(wbit + tj * 16 + col) * RS + bo + kk + quad * 8]);
                #pragma unroll
                for (int ti = 0; ti < 4; ++ti)
                    #pragma unroll
                    for (int tj = 0; tj < 4; ++tj)
                        acc[ti][tj] = __builtin_amdgcn_mfma_f32_16x16x32_bf16(
                            af[ti], bfr[tj], acc[ti][tj], 0, 0, 0);
            }
        }
    }

    // Sign-pack via ballot; C/D layout (m89): col=lane&15, row=quad*4+reg.
    // TRANSPOSED store: codes_t[word][row].
    #pragma unroll
    for (int ti = 0; ti < 4; ++ti) {
        #pragma unroll
        for (int rg = 0; rg < 4; ++rg) {
            unsigned long long b[4];
            #pragma unroll
            for (int tj = 0; tj < 4; ++tj)
                b[tj] = __ballot(acc[ti][tj][rg] > 0.f);
            if (col < 2) {
                const int w = col;
                unsigned int lo16 = (unsigned int)(b[2 * w]     >> (16 * quad)) & 0xFFFFu;
                unsigned int hi16 = (unsigned int)(b[2 * w + 1] >> (16 * quad)) & 0xFFFFu;
                const int row = row0 + wrow + ti * 16 + quad * 4 + rg;
                const int wg  = blockIdx.y * 4 + (wv & 1) * 2 + w;
                codes_t[(size_t)wg * NROWS + row] = lo16 | (hi16 << 16);
            }
        }
    }
}

// ---------------- Stage 2: Hamming -> cos LUT -> mask -> out ----------------
// grid: 512 blocks (l, b, 2 a-halves, 4 doc-chunks), block 256 = 1 doc/thread.
// Doc code register-resident (coalesced via codes_t); 32 q-codes in LDS read
// as wave-uniform broadcasts (conflict-free). VALU:LDS ~8:1 -> VALU-bound.
__global__ __launch_bounds__(256) void simmat_kernel(
    const unsigned int* __restrict__ codes_t,
    const int* __restrict__ qtok, const int* __restrict__ dtok,
    float* __restrict__ out)
{
    __shared__ unsigned int qc[32 * 36];  // 32 a-rows, stride 36 (16B-aligned)
    __shared__ float lut[NBITS_ + 1];
    __shared__ float qm[32];

    const int blk = blockIdx.x;
    const int ct  = blk & 3;
    const int ah  = (blk >> 2) & 1;
    const int b   = (blk >> 3) & 31;
    const int l   = blk >> 8;
    const int t   = threadIdx.x;

    for (int h = t; h <= NBITS_; h += 256)
        lut[h] = cosf((float)M_PI / (float)NBITS_ * (float)h);

    const int a0 = ah * 32;
    const int qrow0 = (l * BAT_ + b) * A_ + a0;
    // stage 32x32 query words, coalesced: idx -> (w=idx>>5, a=idx&31)
    #pragma unroll
    for (int i = 0; i < 4; ++i) {
        int idx = i * 256 + t;            // [0, 1024)
        int w = idx >> 5, a = idx & 31;
        qc[a * 36 + w] = codes_t[(size_t)w * NROWS + qrow0 + a];
    }
    if (t < 32) qm[t] = (qtok[b * A_ + a0 + t] != 0) ? 1.f : 0.f;
    __syncthreads();

    const int c = ct * 256 + t;
    const size_t drow = (size_t)NQROWS + (size_t)(l * BAT_ + b) * B_ + c;
    unsigned int dc[NW];
    #pragma unroll
    for (int w = 0; w < NW; ++w) dc[w] = codes_t[(size_t)w * NROWS + drow];
    const float dm = (dtok[b * B_ + c] != 0) ? 1.f : 0.f;

    float* obase = out + ((size_t)((b * L_ + l) * A_ + a0)) * B_ + c;
    #pragma unroll 4
    for (int ai = 0; ai < 32; ++ai) {
        int ham = 0;
        #pragma unroll
        for (int m = 0; m < 8; ++m) {
            uint4 qv = *(const uint4*)(&qc[ai * 36 + m * 4]);  // wave-uniform bcast
            ham += __popc(qv.x ^ dc[4 * m])     + __popc(qv.y ^ dc[4 * m + 1])
                 + __popc(qv.z ^ dc[4 * m + 2]) + __popc(qv.w ^ dc[4 * m + 3]);
        }
        obase[(size_t)ai * B_] = lut[ham] * (qm[ai] * dm);
    }
}

extern "C" void kernel_launch(void* const* d_in, const int* in_sizes, int n_in,
                              void* d_out, int out_size, void* d_ws, size_t ws_size,
                              hipStream_t stream) {
    const float* qe  = (const float*)d_in[0];  // [L,BAT,A,D]
    const float* de  = (const float*)d_in[1];  // [L,BAT,B,D]
    const int* qtok  = (const int*)d_in[2];    // [BAT,A]
    const int* dtok  = (const int*)d_in[3];    // [BAT,B]
    const float* r   = (const float*)d_in[4];  // [NBITS,D]
    float* out = (float*)d_out;                // [BAT,L,A,B] fp32
    unsigned int* codes_t = (unsigned int*)d_ws; // [NW][NROWS] = 8.9 MB

    dim3 g1(NROWS / TM, NBITS_ / TN);
    hash_kernel<<<g1, 256, 0, stream>>>(qe, de, r, codes_t);
    simmat_kernel<<<L_ * BAT_ * 2 * 4, 256, 0, stream>>>(codes_t, qtok, dtok, out);
}

// Round 9
// 169.377 us; speedup vs baseline: 1.3870x; 1.0219x over previous
//
#include <hip/hip_runtime.h>
#include <math.h>

#define L_ 2
#define BAT_ 32
#define A_ 64
#define B_ 1024
#define D_ 128
#define NBITS_ 1024
#define NW 32                 // u32 words per code (1024 bits)
#define NQROWS (L_*BAT_*A_)   // 4096
#define NDROWS (L_*BAT_*B_)   // 65536
#define NROWS (NQROWS + NDROWS) // 69632

#define TM 128                // rows per block
#define TN 128                // bits per block
#define KH 64                 // K staged in halves
// LDS row: [hi 0..63 | lo 64..127 | pad 8] bf16 -> stride 136 elts = 272 B
#define RS 136

typedef __bf16 bf16x4 __attribute__((ext_vector_type(4)));
typedef __bf16 bf16x8 __attribute__((ext_vector_type(8)));
typedef float  f32x4  __attribute__((ext_vector_type(4)));

// ---------------- Stage 1: LSH sign-hash (bf16-split MFMA + ballot pack) ----
// UNCHANGED from R8 (82-85 us measured). Stores codes transposed:
// codes_t[word][row] so stage 2 reads coalesce.
__global__ __launch_bounds__(256) void hash_kernel(
    const float* __restrict__ qe, const float* __restrict__ de,
    const float* __restrict__ r, unsigned int* __restrict__ codes_t)
{
    __shared__ __align__(16) __bf16 As[TM * RS];   // 34816 B
    __shared__ __align__(16) __bf16 Bs[TN * RS];   // 34816 B

    const int t = threadIdx.x;
    const int row0 = blockIdx.x * TM;   // 4096 % 128 == 0: no q/d straddle
    const int bit0 = blockIdx.y * TN;

    const float* abase = (row0 < NQROWS) ? (qe + (size_t)row0 * D_)
                                         : (de + (size_t)(row0 - NQROWS) * D_);
    const float* bbase = r + (size_t)bit0 * D_;

    const int wv   = t >> 6;          // wave 0..3
    const int lane = t & 63;
    const int quad = lane >> 4;       // 0..3
    const int col  = lane & 15;       // 0..15
    const int wrow = (wv >> 1) * 64;  // wave's row offset in block tile
    const int wbit = (wv & 1) * 64;   // wave's bit offset in block tile

    f32x4 acc[4][4];
    #pragma unroll
    for (int ti = 0; ti < 4; ++ti)
        #pragma unroll
        for (int tj = 0; tj < 4; ++tj)
            acc[ti][tj] = (f32x4){0.f, 0.f, 0.f, 0.f};

    #pragma unroll
    for (int ks = 0; ks < D_; ks += KH) {
        if (ks) __syncthreads();
        // stage 128x64 fp32 slice of A and B, split into bf16 hi|lo in LDS
        #pragma unroll
        for (int i = 0; i < 8; ++i) {
            int f = (t + i * 256) * 4;      // flat idx in 128x64 tile
            int rr = f >> 6, cc = f & 63;
            float4 v = *(const float4*)(abase + (size_t)rr * D_ + ks + cc);
            bf16x4 hi, lo;
            hi[0] = (__bf16)v.x; hi[1] = (__bf16)v.y;
            hi[2] = (__bf16)v.z; hi[3] = (__bf16)v.w;
            lo[0] = (__bf16)(v.x - (float)hi[0]);
            lo[1] = (__bf16)(v.y - (float)hi[1]);
            lo[2] = (__bf16)(v.z - (float)hi[2]);
            lo[3] = (__bf16)(v.w - (float)hi[3]);
            *(bf16x4*)(&As[rr * RS + cc])      = hi;
            *(bf16x4*)(&As[rr * RS + 64 + cc]) = lo;
        }
        #pragma unroll
        for (int i = 0; i < 8; ++i) {
            int f = (t + i * 256) * 4;
            int rr = f >> 6, cc = f & 63;
            float4 v = *(const float4*)(bbase + (size_t)rr * D_ + ks + cc);
            bf16x4 hi, lo;
            hi[0] = (__bf16)v.x; hi[1] = (__bf16)v.y;
            hi[2] = (__bf16)v.z; hi[3] = (__bf16)v.w;
            lo[0] = (__bf16)(v.x - (float)hi[0]);
            lo[1] = (__bf16)(v.y - (float)hi[1]);
            lo[2] = (__bf16)(v.z - (float)hi[2]);
            lo[3] = (__bf16)(v.w - (float)hi[3]);
            *(bf16x4*)(&Bs[rr * RS + cc])      = hi;
            *(bf16x4*)(&Bs[rr * RS + 64 + cc]) = lo;
        }
        __syncthreads();

        // 3 segments: (A-off, B-off) = (hi,hi), (hi,lo), (lo,hi)
        #pragma unroll
        for (int seg = 0; seg < 3; ++seg) {
            const int ao = (seg == 2) ? 64 : 0;
            const int bo = (seg == 1) ? 64 : 0;
            #pragma unroll
            for (int kk = 0; kk < KH; kk += 32) {
                bf16x8 af[4], bfr[4];
                #pragma unroll
                for (int ti = 0; ti < 4; ++ti)
                    af[ti] = *(const bf16x8*)(
                        &As[(wrow + ti * 16 + col) * RS + ao + kk + quad * 8]);
                #pragma unroll
                for (int tj = 0; tj < 4; ++tj)
                    bfr[tj] = *(const bf16x8*)(
                        &Bs[(wbit + tj * 16 + col) * RS + bo + kk + quad * 8]);
                #pragma unroll
                for (int ti = 0; ti < 4; ++ti)
                    #pragma unroll
                    for (int tj = 0; tj < 4; ++tj)
                        acc[ti][tj] = __builtin_amdgcn_mfma_f32_16x16x32_bf16(
                            af[ti], bfr[tj], acc[ti][tj], 0, 0, 0);
            }
        }
    }

    // Sign-pack via ballot; C/D layout (m89): col=lane&15, row=quad*4+reg.
    // TRANSPOSED store: codes_t[word][row].
    #pragma unroll
    for (int ti = 0; ti < 4; ++ti) {
        #pragma unroll
        for (int rg = 0; rg < 4; ++rg) {
            unsigned long long b[4];
            #pragma unroll
            for (int tj = 0; tj < 4; ++tj)
                b[tj] = __ballot(acc[ti][tj][rg] > 0.f);
            if (col < 2) {
                const int w = col;
                unsigned int lo16 = (unsigned int)(b[2 * w]     >> (16 * quad)) & 0xFFFFu;
                unsigned int hi16 = (unsigned int)(b[2 * w + 1] >> (16 * quad)) & 0xFFFFu;
                const int row = row0 + wrow + ti * 16 + quad * 4 + rg;
                const int wg  = blockIdx.y * 4 + (wv & 1) * 2 + w;
                codes_t[(size_t)wg * NROWS + row] = lo16 | (hi16 << 16);
            }
        }
    }
}

// ---------------- Stage 2: Hamming -> cos (HW v_cos) -> mask -> out ---------
// grid: 2048 blocks (l, b, 8 a-chunks, 4 doc-chunks), block 256 = 1 doc each.
// 8 blocks/CU = 32 waves/CU (full occupancy). No LUT: sim via __cosf (HW
// v_cos path) — removes divergent LDS reads and the 1025-entry init.
// qc reads are wave-uniform LDS broadcasts; q-mask is a uniform scalar load.
__global__ __launch_bounds__(256) void simmat_kernel(
    const unsigned int* __restrict__ codes_t,
    const int* __restrict__ qtok, const int* __restrict__ dtok,
    float* __restrict__ out)
{
    __shared__ unsigned int qc[8 * 36];   // 8 a-rows, stride 36 (16B-aligned)

    const int blk  = blockIdx.x;
    const int ct   = blk & 3;
    const int asub = (blk >> 2) & 7;
    const int b    = (blk >> 5) & 31;
    const int l    = blk >> 10;
    const int t    = threadIdx.x;

    const int a0 = asub * 8;
    const int qrow0 = (l * BAT_ + b) * A_ + a0;
    // stage 8x32 query words: t -> (w = t>>3, a = t&7), coalesced in rows
    if (t < 256) {
        int w = t >> 3, a = t & 7;
        qc[a * 36 + w] = codes_t[(size_t)w * NROWS + qrow0 + a];
    }
    __syncthreads();

    const int c = ct * 256 + t;
    const size_t drow = (size_t)NQROWS + (size_t)(l * BAT_ + b) * B_ + c;
    unsigned int dc[NW];
    #pragma unroll
    for (int w = 0; w < NW; ++w) dc[w] = codes_t[(size_t)w * NROWS + drow];
    const float dm = (dtok[b * B_ + c] != 0) ? 1.f : 0.f;

    float* obase = out + ((size_t)((b * L_ + l) * A_ + a0)) * B_ + c;
    #pragma unroll
    for (int ai = 0; ai < 8; ++ai) {
        int ham = 0;
        #pragma unroll
        for (int m = 0; m < 8; ++m) {
            uint4 qv = *(const uint4*)(&qc[ai * 36 + m * 4]);  // uniform bcast
            ham += __popc(qv.x ^ dc[4 * m])     + __popc(qv.y ^ dc[4 * m + 1])
                 + __popc(qv.z ^ dc[4 * m + 2]) + __popc(qv.w ^ dc[4 * m + 3]);
        }
        const float qmv = (qtok[b * A_ + a0 + ai] != 0) ? 1.f : 0.f; // uniform
        float sim = __cosf((float)M_PI / (float)NBITS_ * (float)ham);
        obase[(size_t)ai * B_] = sim * (qmv * dm);
    }
}

extern "C" void kernel_launch(void* const* d_in, const int* in_sizes, int n_in,
                              void* d_out, int out_size, void* d_ws, size_t ws_size,
                              hipStream_t stream) {
    const float* qe  = (const float*)d_in[0];  // [L,BAT,A,D]
    const float* de  = (const float*)d_in[1];  // [L,BAT,B,D]
    const int* qtok  = (const int*)d_in[2];    // [BAT,A]
    const int* dtok  = (const int*)d_in[3];    // [BAT,B]
    const float* r   = (const float*)d_in[4];  // [NBITS,D]
    float* out = (float*)d_out;                // [BAT,L,A,B] fp32
    unsigned int* codes_t = (unsigned int*)d_ws; // [NW][NROWS] = 8.9 MB

    dim3 g1(NROWS / TM, NBITS_ / TN);
    hash_kernel<<<g1, 256, 0, stream>>>(qe, de, r, codes_t);
    simmat_kernel<<<L_ * BAT_ * 8 * 4, 256, 0, stream>>>(codes_t, qtok, dtok, out);
}